// Round 1
// baseline (557.669 us; speedup 1.0000x reference)
//
#include <hip/hip_runtime.h>
#include <hip/hip_bf16.h>
#include <math.h>

#define D_MODEL 1024
#define SEQ 1024
#define BATCH 16
#define NROWS (BATCH * SEQ)   // 16384

typedef __bf16 bf16x8 __attribute__((ext_vector_type(8)));
typedef float f32x4 __attribute__((ext_vector_type(4)));
typedef __hip_bfloat16 bf16;

__device__ __forceinline__ float bf2f(bf16 v) { return __bfloat162float(v); }
__device__ __forceinline__ bf16 f2bf(float v) { return __float2bfloat16(v); }

// ---------------- weight fp32 -> bf16 ----------------
__global__ void conv_w_kernel(const float* __restrict__ src, bf16* __restrict__ dst, int n) {
    int i = blockIdx.x * blockDim.x + threadIdx.x;
    int stride = gridDim.x * blockDim.x;
    for (; i < n; i += stride) dst[i] = f2bf(src[i]);
}

// ---------------- layernorm per row ----------------
__global__ __launch_bounds__(256) void ln_kernel(
    const float* __restrict__ x, const float* __restrict__ gamma,
    const float* __restrict__ beta, bf16* __restrict__ xn)
{
    const int row = blockIdx.x;
    const int tid = threadIdx.x;
    const size_t base = (size_t)row * D_MODEL;
    float4 v = *reinterpret_cast<const float4*>(x + base + tid * 4);
    float s  = v.x + v.y + v.z + v.w;
    float s2 = v.x * v.x + v.y * v.y + v.z * v.z + v.w * v.w;
    for (int off = 32; off > 0; off >>= 1) {
        s  += __shfl_down(s, off);
        s2 += __shfl_down(s2, off);
    }
    __shared__ float red[10];
    int wv = tid >> 6;
    if ((tid & 63) == 0) { red[wv] = s; red[4 + wv] = s2; }
    __syncthreads();
    if (tid == 0) {
        float ts = red[0] + red[1] + red[2] + red[3];
        float t2 = red[4] + red[5] + red[6] + red[7];
        float mu = ts * (1.0f / D_MODEL);
        float var = t2 * (1.0f / D_MODEL) - mu * mu;
        red[8] = mu;
        red[9] = rsqrtf(var + 1e-5f);
    }
    __syncthreads();
    float mu = red[8], rstd = red[9];
    float4 g = *reinterpret_cast<const float4*>(gamma + tid * 4);
    float4 b = *reinterpret_cast<const float4*>(beta + tid * 4);
    bf16* o = xn + base + tid * 4;
    o[0] = f2bf((v.x - mu) * rstd * g.x + b.x);
    o[1] = f2bf((v.y - mu) * rstd * g.y + b.y);
    o[2] = f2bf((v.z - mu) * rstd * g.z + b.z);
    o[3] = f2bf((v.w - mu) * rstd * g.w + b.w);
}

// ---------------- time-mix ----------------
__global__ __launch_bounds__(256) void mix_kernel(
    const bf16* __restrict__ xn,
    const float* __restrict__ tmk, const float* __restrict__ tmv, const float* __restrict__ tmr,
    bf16* __restrict__ xk, bf16* __restrict__ xv, bf16* __restrict__ xr)
{
    size_t i = (size_t)blockIdx.x * blockDim.x + threadIdx.x;  // one elem per thread, grid exact
    int d = (int)(i & (D_MODEL - 1));
    int row = (int)(i >> 10);
    int t = row & (SEQ - 1);
    float cur = bf2f(xn[i]);
    float prev = (t == 0) ? 0.0f : bf2f(xn[i - D_MODEL]);
    float mk = tmk[d], mv = tmv[d], mr = tmr[d];
    xk[i] = f2bf(mk * cur + (1.0f - mk) * prev);
    xv[i] = f2bf(mv * cur + (1.0f - mv) * prev);
    xr[i] = f2bf(mr * cur + (1.0f - mr) * prev);
}

// ---------------- fused 3x GEMM (k,v,r) with ternary/sigmoid epilogue ----------------
// C[m,e] = sum_d A[m,d] * W[e,d]; A row-major MxK, W row-major NxK (K contiguous both)
__global__ __launch_bounds__(256) void gemm_kvr_kernel(
    const bf16* __restrict__ Xk, const bf16* __restrict__ Xv, const bf16* __restrict__ Xr,
    const bf16* __restrict__ Wk, const bf16* __restrict__ Wv, const bf16* __restrict__ Wr,
    bf16* __restrict__ KV, bf16* __restrict__ R)
{
    const int m0 = blockIdx.y * 64;
    const int n0 = blockIdx.x * 64;
    const int tid = threadIdx.x;
    const int lane = tid & 63, wave = tid >> 6;
    const int wm = wave >> 1, wn = wave & 1;
    const int mf = lane & 15, quad = lane >> 4;

    __shared__ bf16 Ak[64][32], Av[64][32], Ar[64][32];
    __shared__ bf16 Bk[64][32], Bv[64][32], Br[64][32];

    const f32x4 zero = {0.f, 0.f, 0.f, 0.f};
    f32x4 ck[2][2], cv[2][2], cr[2][2];
    for (int i = 0; i < 2; i++)
        for (int j = 0; j < 2; j++) { ck[i][j] = zero; cv[i][j] = zero; cr[i][j] = zero; }

    const int lr = tid >> 2;          // 0..63 tile row
    const int lc = (tid & 3) * 8;     // col start (8 bf16 = 16B)

    for (int k0 = 0; k0 < D_MODEL; k0 += 32) {
        __syncthreads();
        const size_t ga = (size_t)(m0 + lr) * D_MODEL + k0 + lc;
        const size_t gb = (size_t)(n0 + lr) * D_MODEL + k0 + lc;
        *reinterpret_cast<uint4*>(&Ak[lr][lc]) = *reinterpret_cast<const uint4*>(Xk + ga);
        *reinterpret_cast<uint4*>(&Av[lr][lc]) = *reinterpret_cast<const uint4*>(Xv + ga);
        *reinterpret_cast<uint4*>(&Ar[lr][lc]) = *reinterpret_cast<const uint4*>(Xr + ga);
        *reinterpret_cast<uint4*>(&Bk[lr][lc]) = *reinterpret_cast<const uint4*>(Wk + gb);
        *reinterpret_cast<uint4*>(&Bv[lr][lc]) = *reinterpret_cast<const uint4*>(Wv + gb);
        *reinterpret_cast<uint4*>(&Br[lr][lc]) = *reinterpret_cast<const uint4*>(Wr + gb);
        __syncthreads();

        bf16x8 fak[2], fav[2], far_[2], fbk[2], fbv[2], fbr[2];
        for (int i = 0; i < 2; i++) {
            const int ar_ = wm * 32 + i * 16 + mf;
            const int br_ = wn * 32 + i * 16 + mf;
            fak[i]  = *reinterpret_cast<const bf16x8*>(&Ak[ar_][quad * 8]);
            fav[i]  = *reinterpret_cast<const bf16x8*>(&Av[ar_][quad * 8]);
            far_[i] = *reinterpret_cast<const bf16x8*>(&Ar[ar_][quad * 8]);
            fbk[i]  = *reinterpret_cast<const bf16x8*>(&Bk[br_][quad * 8]);
            fbv[i]  = *reinterpret_cast<const bf16x8*>(&Bv[br_][quad * 8]);
            fbr[i]  = *reinterpret_cast<const bf16x8*>(&Br[br_][quad * 8]);
        }
        for (int i = 0; i < 2; i++)
            for (int j = 0; j < 2; j++) {
                ck[i][j] = __builtin_amdgcn_mfma_f32_16x16x32_bf16(fak[i],  fbk[j], ck[i][j], 0, 0, 0);
                cv[i][j] = __builtin_amdgcn_mfma_f32_16x16x32_bf16(fav[i],  fbv[j], cv[i][j], 0, 0, 0);
                cr[i][j] = __builtin_amdgcn_mfma_f32_16x16x32_bf16(far_[i], fbr[j], cr[i][j], 0, 0, 0);
            }
    }

    for (int i = 0; i < 2; i++)
        for (int j = 0; j < 2; j++)
            for (int e = 0; e < 4; e++) {
                int row = m0 + wm * 32 + i * 16 + quad * 4 + e;
                int col = n0 + wn * 32 + j * 16 + mf;
                float kk = ck[i][j][e];
                kk = (kk > 0.5f) ? 1.0f : ((kk < -0.5f) ? -1.0f : 0.0f);
                float vv = cv[i][j][e];
                vv = (vv > 0.5f) ? 1.0f : ((vv < -0.5f) ? -1.0f : 0.0f);
                float rr = 1.0f / (1.0f + expf(-cr[i][j][e]));
                size_t o = (size_t)row * D_MODEL + col;
                KV[o] = f2bf(kk * vv);
                R[o]  = f2bf(rr);
            }
}

// ---------------- recurrent scan over T ----------------
__global__ __launch_bounds__(64) void scan_kernel(
    const bf16* __restrict__ kv, const float* __restrict__ dw,
    const float* __restrict__ S0, bf16* __restrict__ sall, float* __restrict__ sfinal)
{
    int c = blockIdx.x * 64 + threadIdx.x;  // 0..16383  (b*D + d)
    int d = c & (D_MODEL - 1);
    int b = c >> 10;
    float dec = 1.0f / (1.0f + expf(-dw[d]));
    float S = S0[c];
    size_t idx = (size_t)b * SEQ * D_MODEL + d;
    for (int t = 0; t < SEQ; t++, idx += D_MODEL) {
        S = dec * S + bf2f(kv[idx]);
        sall[idx] = f2bf(S);
    }
    sfinal[c] = S;
}

// ---------------- output GEMM with residual epilogue ----------------
__global__ __launch_bounds__(256) void gemm_out_kernel(
    const bf16* __restrict__ SA, const bf16* __restrict__ Wo,
    const bf16* __restrict__ R, const float* __restrict__ x, float* __restrict__ out)
{
    const int m0 = blockIdx.y * 64;
    const int n0 = blockIdx.x * 64;
    const int tid = threadIdx.x;
    const int lane = tid & 63, wave = tid >> 6;
    const int wm = wave >> 1, wn = wave & 1;
    const int mf = lane & 15, quad = lane >> 4;

    __shared__ bf16 As[64][32], Bs[64][32];
    const f32x4 zero = {0.f, 0.f, 0.f, 0.f};
    f32x4 c[2][2];
    for (int i = 0; i < 2; i++) for (int j = 0; j < 2; j++) c[i][j] = zero;

    const int lr = tid >> 2, lc = (tid & 3) * 8;

    for (int k0 = 0; k0 < D_MODEL; k0 += 32) {
        __syncthreads();
        *reinterpret_cast<uint4*>(&As[lr][lc]) =
            *reinterpret_cast<const uint4*>(SA + (size_t)(m0 + lr) * D_MODEL + k0 + lc);
        *reinterpret_cast<uint4*>(&Bs[lr][lc]) =
            *reinterpret_cast<const uint4*>(Wo + (size_t)(n0 + lr) * D_MODEL + k0 + lc);
        __syncthreads();
        bf16x8 fa[2], fb[2];
        for (int i = 0; i < 2; i++) {
            fa[i] = *reinterpret_cast<const bf16x8*>(&As[wm * 32 + i * 16 + mf][quad * 8]);
            fb[i] = *reinterpret_cast<const bf16x8*>(&Bs[wn * 32 + i * 16 + mf][quad * 8]);
        }
        for (int i = 0; i < 2; i++)
            for (int j = 0; j < 2; j++)
                c[i][j] = __builtin_amdgcn_mfma_f32_16x16x32_bf16(fa[i], fb[j], c[i][j], 0, 0, 0);
    }

    for (int i = 0; i < 2; i++)
        for (int j = 0; j < 2; j++)
            for (int e = 0; e < 4; e++) {
                int row = m0 + wm * 32 + i * 16 + quad * 4 + e;
                int col = n0 + wn * 32 + j * 16 + mf;
                size_t o = (size_t)row * D_MODEL + col;
                out[o] = x[o] + bf2f(R[o]) * c[i][j][e];
            }
}

extern "C" void kernel_launch(void* const* d_in, const int* in_sizes, int n_in,
                              void* d_out, int out_size, void* d_ws, size_t ws_size,
                              hipStream_t stream) {
    const float* x     = (const float*)d_in[0];
    const float* S0    = (const float*)d_in[1];
    const float* gamma = (const float*)d_in[2];
    const float* beta  = (const float*)d_in[3];
    const float* tmk   = (const float*)d_in[4];
    const float* tmv   = (const float*)d_in[5];
    const float* tmr   = (const float*)d_in[6];
    const float* dw    = (const float*)d_in[7];
    const float* Wk    = (const float*)d_in[8];
    const float* Wv    = (const float*)d_in[9];
    const float* Wr    = (const float*)d_in[10];
    const float* Wo    = (const float*)d_in[11];
    float* out = (float*)d_out;

    const int WN = D_MODEL * D_MODEL;       // 1048576
    const size_t MATN = (size_t)NROWS * D_MODEL;  // 16777216

    bf16* wsb  = (bf16*)d_ws;
    bf16* Wk_b = wsb;
    bf16* Wv_b = Wk_b + WN;
    bf16* Wr_b = Wv_b + WN;
    bf16* Wo_b = Wr_b + WN;
    bf16* XN   = Wo_b + WN;       // x_norm; reused as KV after mix
    bf16* XK   = XN + MATN;       // xk; reused as S_all after gemm_kvr
    bf16* XV   = XK + MATN;
    bf16* XR   = XV + MATN;
    bf16* RB   = XR + MATN;
    bf16* KV   = XN;   // x_norm dead after mix_kernel
    bf16* SA   = XK;   // xk dead after gemm_kvr_kernel

    conv_w_kernel<<<1024, 256, 0, stream>>>(Wk, Wk_b, WN);
    conv_w_kernel<<<1024, 256, 0, stream>>>(Wv, Wv_b, WN);
    conv_w_kernel<<<1024, 256, 0, stream>>>(Wr, Wr_b, WN);
    conv_w_kernel<<<1024, 256, 0, stream>>>(Wo, Wo_b, WN);

    ln_kernel<<<NROWS, 256, 0, stream>>>(x, gamma, beta, XN);

    mix_kernel<<<(int)(MATN / 256), 256, 0, stream>>>(XN, tmk, tmv, tmr, XK, XV, XR);

    gemm_kvr_kernel<<<dim3(D_MODEL / 64, NROWS / 64), 256, 0, stream>>>(
        XK, XV, XR, Wk_b, Wv_b, Wr_b, KV, RB);

    scan_kernel<<<NROWS * D_MODEL / SEQ / 64, 64, 0, stream>>>(
        KV, dw, S0, SA, out + MATN);

    gemm_out_kernel<<<dim3(D_MODEL / 64, NROWS / 64), 256, 0, stream>>>(
        SA, Wo_b, RB, x, out);
}

// Round 2
// 449.850 us; speedup vs baseline: 1.2397x; 1.2397x over previous
//
#include <hip/hip_runtime.h>
#include <hip/hip_bf16.h>
#include <math.h>

#define D_MODEL 1024
#define SEQ 1024
#define BATCH 16
#define NROWS (BATCH * SEQ)   // 16384

typedef __bf16 bf16x8 __attribute__((ext_vector_type(8)));
typedef __bf16 bf16x4 __attribute__((ext_vector_type(4)));
typedef float f32x4 __attribute__((ext_vector_type(4)));
typedef __hip_bfloat16 bf16;

__device__ __forceinline__ float bf2f(bf16 v) { return __bfloat162float(v); }
__device__ __forceinline__ bf16 f2bf(float v) { return __float2bfloat16(v); }

__device__ __forceinline__ void gload_lds16(const bf16* g, bf16* l) {
    __builtin_amdgcn_global_load_lds(
        (const __attribute__((address_space(1))) void*)g,
        (__attribute__((address_space(3))) void*)l, 16, 0, 0);
}

// ---------------- weight fp32 -> bf16 ----------------
__global__ void conv_w_kernel(const float* __restrict__ src, bf16* __restrict__ dst, int n) {
    int i = blockIdx.x * blockDim.x + threadIdx.x;
    int stride = gridDim.x * blockDim.x;
    for (; i < n; i += stride) dst[i] = f2bf(src[i]);
}

// ---------------- fused LayerNorm + time-mix: one wave per row ----------------
// prev_norm(t) = LN(x[t-1]) recomputed here; zeros at t==0 (reference semantics).
__global__ __launch_bounds__(256) void lnmix_kernel(
    const float* __restrict__ x, const float* __restrict__ gamma, const float* __restrict__ beta,
    const float* __restrict__ tmk, const float* __restrict__ tmv, const float* __restrict__ tmr,
    bf16* __restrict__ xk, bf16* __restrict__ xv, bf16* __restrict__ xr)
{
    const int wave = threadIdx.x >> 6, lane = threadIdx.x & 63;
    const int row = blockIdx.x * 4 + wave;
    const int t = row & (SEQ - 1);
    const size_t base = (size_t)row * D_MODEL;

    float4 vc[4], vp[4];
    float sc = 0.f, sc2 = 0.f, sp = 0.f, sp2 = 0.f;
#pragma unroll
    for (int c = 0; c < 4; c++) {
        const int d = lane * 4 + c * 256;
        vc[c] = *reinterpret_cast<const float4*>(x + base + d);
        if (t == 0) { vp[c] = make_float4(0.f, 0.f, 0.f, 0.f); }
        else        { vp[c] = *reinterpret_cast<const float4*>(x + base - D_MODEL + d); }
        sc  += vc[c].x + vc[c].y + vc[c].z + vc[c].w;
        sc2 += vc[c].x * vc[c].x + vc[c].y * vc[c].y + vc[c].z * vc[c].z + vc[c].w * vc[c].w;
        sp  += vp[c].x + vp[c].y + vp[c].z + vp[c].w;
        sp2 += vp[c].x * vp[c].x + vp[c].y * vp[c].y + vp[c].z * vp[c].z + vp[c].w * vp[c].w;
    }
#pragma unroll
    for (int off = 1; off < 64; off <<= 1) {
        sc  += __shfl_xor(sc, off);
        sc2 += __shfl_xor(sc2, off);
        sp  += __shfl_xor(sp, off);
        sp2 += __shfl_xor(sp2, off);
    }
    const float muc = sc * (1.0f / D_MODEL);
    const float rc  = rsqrtf(sc2 * (1.0f / D_MODEL) - muc * muc + 1e-5f);
    const float mup = sp * (1.0f / D_MODEL);
    const float rp  = rsqrtf(sp2 * (1.0f / D_MODEL) - mup * mup + 1e-5f);

#pragma unroll
    for (int c = 0; c < 4; c++) {
        const int d = lane * 4 + c * 256;
        float4 g  = *reinterpret_cast<const float4*>(gamma + d);
        float4 b  = *reinterpret_cast<const float4*>(beta + d);
        float4 mk = *reinterpret_cast<const float4*>(tmk + d);
        float4 mv = *reinterpret_cast<const float4*>(tmv + d);
        float4 mr = *reinterpret_cast<const float4*>(tmr + d);
        float cn[4], pn[4];
        cn[0] = (vc[c].x - muc) * rc * g.x + b.x;
        cn[1] = (vc[c].y - muc) * rc * g.y + b.y;
        cn[2] = (vc[c].z - muc) * rc * g.z + b.z;
        cn[3] = (vc[c].w - muc) * rc * g.w + b.w;
        if (t == 0) { pn[0] = pn[1] = pn[2] = pn[3] = 0.f; }
        else {
            pn[0] = (vp[c].x - mup) * rp * g.x + b.x;
            pn[1] = (vp[c].y - mup) * rp * g.y + b.y;
            pn[2] = (vp[c].z - mup) * rp * g.z + b.z;
            pn[3] = (vp[c].w - mup) * rp * g.w + b.w;
        }
        const float mkv[4] = {mk.x, mk.y, mk.z, mk.w};
        const float mvv[4] = {mv.x, mv.y, mv.z, mv.w};
        const float mrv[4] = {mr.x, mr.y, mr.z, mr.w};
        bf16x4 ok, ov, orr;
#pragma unroll
        for (int e = 0; e < 4; e++) {
            ok[e]  = (__bf16)(mkv[e] * cn[e] + (1.0f - mkv[e]) * pn[e]);
            ov[e]  = (__bf16)(mvv[e] * cn[e] + (1.0f - mvv[e]) * pn[e]);
            orr[e] = (__bf16)(mrv[e] * cn[e] + (1.0f - mrv[e]) * pn[e]);
        }
        *reinterpret_cast<bf16x4*>(xk + base + d) = ok;
        *reinterpret_cast<bf16x4*>(xv + base + d) = ov;
        *reinterpret_cast<bf16x4*>(xr + base + d) = orr;
    }
}

// ---------------- m97-style GEMM: C[m,n] = sum_k A[m,k] * W[n,k] ----------------
// 128x128 block tile, BK=32, 4 waves each computing 64x64 (4x4 mfma_16x16x32),
// global_load_lds width-16 staging. MODE 0: ternary, 1: sigmoid.
template <int MODE>
__global__ __launch_bounds__(256) void gemm_tn_kernel(
    const bf16* __restrict__ A, const bf16* __restrict__ W, bf16* __restrict__ O)
{
    const int tid = threadIdx.x;
    const int lane = tid & 63, wave = tid >> 6;
    const int wm = wave >> 1, wn = wave & 1;
    const int mf = lane & 15, quad = lane >> 4;
    const int n0 = blockIdx.x * 128;
    const int m0 = blockIdx.y * 128;

    __shared__ bf16 As[128 * 32];
    __shared__ bf16 Bs[128 * 32];

    f32x4 acc[4][4] = {};

    const int r0  = tid >> 2;          // staging row (call 0), rows 0..63
    const int cc0 = (tid & 3) * 8;     // staging col start (8 bf16 = 16B)
    bf16* ldsA0 = As + wave * 512;
    bf16* ldsA1 = As + 2048 + wave * 512;
    bf16* ldsB0 = Bs + wave * 512;
    bf16* ldsB1 = Bs + 2048 + wave * 512;
    const bf16* gA0 = A + (size_t)(m0 + r0) * D_MODEL + cc0;
    const bf16* gA1 = A + (size_t)(m0 + r0 + 64) * D_MODEL + cc0;
    const bf16* gB0 = W + (size_t)(n0 + r0) * D_MODEL + cc0;
    const bf16* gB1 = W + (size_t)(n0 + r0 + 64) * D_MODEL + cc0;

    for (int k0 = 0; k0 < D_MODEL; k0 += 32) {
        __syncthreads();
        gload_lds16(gA0 + k0, ldsA0);
        gload_lds16(gA1 + k0, ldsA1);
        gload_lds16(gB0 + k0, ldsB0);
        gload_lds16(gB1 + k0, ldsB1);
        __syncthreads();
        bf16x8 af[4], bfr[4];
#pragma unroll
        for (int i = 0; i < 4; i++)
            af[i] = *reinterpret_cast<const bf16x8*>(&As[(wm * 64 + i * 16 + mf) * 32 + quad * 8]);
#pragma unroll
        for (int j = 0; j < 4; j++)
            bfr[j] = *reinterpret_cast<const bf16x8*>(&Bs[(wn * 64 + j * 16 + mf) * 32 + quad * 8]);
#pragma unroll
        for (int i = 0; i < 4; i++)
#pragma unroll
            for (int j = 0; j < 4; j++)
                acc[i][j] = __builtin_amdgcn_mfma_f32_16x16x32_bf16(af[i], bfr[j], acc[i][j], 0, 0, 0);
    }

#pragma unroll
    for (int i = 0; i < 4; i++)
#pragma unroll
        for (int j = 0; j < 4; j++)
#pragma unroll
            for (int e = 0; e < 4; e++) {
                const int row = m0 + wm * 64 + i * 16 + quad * 4 + e;
                const int col = n0 + wn * 64 + j * 16 + mf;
                const float v = acc[i][j][e];
                float o;
                if (MODE == 0) o = (v > 0.5f) ? 1.0f : ((v < -0.5f) ? -1.0f : 0.0f);
                else           o = 1.0f / (1.0f + __expf(-v));
                O[(size_t)row * D_MODEL + col] = f2bf(o);
            }
}

// ---------------- output GEMM with residual epilogue ----------------
__global__ __launch_bounds__(256) void gemm_out_kernel(
    const bf16* __restrict__ SA, const bf16* __restrict__ Wo,
    const bf16* __restrict__ R, const float* __restrict__ x, float* __restrict__ out)
{
    const int tid = threadIdx.x;
    const int lane = tid & 63, wave = tid >> 6;
    const int wm = wave >> 1, wn = wave & 1;
    const int mf = lane & 15, quad = lane >> 4;
    const int n0 = blockIdx.x * 128;
    const int m0 = blockIdx.y * 128;

    __shared__ bf16 As[128 * 32];
    __shared__ bf16 Bs[128 * 32];

    f32x4 acc[4][4] = {};

    const int r0  = tid >> 2;
    const int cc0 = (tid & 3) * 8;
    bf16* ldsA0 = As + wave * 512;
    bf16* ldsA1 = As + 2048 + wave * 512;
    bf16* ldsB0 = Bs + wave * 512;
    bf16* ldsB1 = Bs + 2048 + wave * 512;
    const bf16* gA0 = SA + (size_t)(m0 + r0) * D_MODEL + cc0;
    const bf16* gA1 = SA + (size_t)(m0 + r0 + 64) * D_MODEL + cc0;
    const bf16* gB0 = Wo + (size_t)(n0 + r0) * D_MODEL + cc0;
    const bf16* gB1 = Wo + (size_t)(n0 + r0 + 64) * D_MODEL + cc0;

    for (int k0 = 0; k0 < D_MODEL; k0 += 32) {
        __syncthreads();
        gload_lds16(gA0 + k0, ldsA0);
        gload_lds16(gA1 + k0, ldsA1);
        gload_lds16(gB0 + k0, ldsB0);
        gload_lds16(gB1 + k0, ldsB1);
        __syncthreads();
        bf16x8 af[4], bfr[4];
#pragma unroll
        for (int i = 0; i < 4; i++)
            af[i] = *reinterpret_cast<const bf16x8*>(&As[(wm * 64 + i * 16 + mf) * 32 + quad * 8]);
#pragma unroll
        for (int j = 0; j < 4; j++)
            bfr[j] = *reinterpret_cast<const bf16x8*>(&Bs[(wn * 64 + j * 16 + mf) * 32 + quad * 8]);
#pragma unroll
        for (int i = 0; i < 4; i++)
#pragma unroll
            for (int j = 0; j < 4; j++)
                acc[i][j] = __builtin_amdgcn_mfma_f32_16x16x32_bf16(af[i], bfr[j], acc[i][j], 0, 0, 0);
    }

#pragma unroll
    for (int i = 0; i < 4; i++)
#pragma unroll
        for (int j = 0; j < 4; j++)
#pragma unroll
            for (int e = 0; e < 4; e++) {
                const int row = m0 + wm * 64 + i * 16 + quad * 4 + e;
                const int col = n0 + wn * 64 + j * 16 + mf;
                const size_t o = (size_t)row * D_MODEL + col;
                out[o] = x[o] + bf2f(R[o]) * acc[i][j][e];
            }
}

// ---------------- recurrent scan: 4 T-chunks per channel, carry fix-up ----------------
// kv = ternary(k)*ternary(v) computed on the fly.
__global__ __launch_bounds__(256) void scan_kernel(
    const bf16* __restrict__ K, const bf16* __restrict__ V,
    const float* __restrict__ dw, const float* __restrict__ S0,
    bf16* __restrict__ sall, float* __restrict__ sfinal)
{
    const int ch = threadIdx.x & 63;   // channel within group
    const int q  = threadIdx.x >> 6;   // T-chunk 0..3
    const int d  = blockIdx.x * 64 + ch;
    const int b  = blockIdx.y;
    const float dec = 1.0f / (1.0f + __expf(-dw[d]));
    float c256 = dec;
#pragma unroll
    for (int i = 0; i < 8; i++) c256 *= c256;   // dec^256

    const size_t base = ((size_t)b * SEQ + q * 256) * D_MODEL + d;

    // pass 1: local scan (zero-init), chunk-final only
    float S = 0.f;
    size_t idx = base;
    for (int t = 0; t < 256; t++, idx += D_MODEL)
        S = dec * S + bf2f(K[idx]) * bf2f(V[idx]);

    __shared__ float Lf[4][64];
    __shared__ float P[4][64];
    Lf[q][ch] = S;
    __syncthreads();
    if (q == 0) {
        float p = S0[b * D_MODEL + d];      // true S_{-1}
        P[0][ch] = p;
        p = Lf[0][ch] + c256 * p; P[1][ch] = p;
        p = Lf[1][ch] + c256 * p; P[2][ch] = p;
        p = Lf[2][ch] + c256 * p; P[3][ch] = p;
        p = Lf[3][ch] + c256 * p;
        sfinal[b * D_MODEL + d] = p;
    }
    __syncthreads();

    // pass 2: scan with true incoming carry as init, store
    float Sv = P[q][ch];
    idx = base;
    for (int t = 0; t < 256; t++, idx += D_MODEL) {
        Sv = dec * Sv + bf2f(K[idx]) * bf2f(V[idx]);
        sall[idx] = f2bf(Sv);
    }
}

extern "C" void kernel_launch(void* const* d_in, const int* in_sizes, int n_in,
                              void* d_out, int out_size, void* d_ws, size_t ws_size,
                              hipStream_t stream) {
    const float* x     = (const float*)d_in[0];
    const float* S0    = (const float*)d_in[1];
    const float* gamma = (const float*)d_in[2];
    const float* beta  = (const float*)d_in[3];
    const float* tmk   = (const float*)d_in[4];
    const float* tmv   = (const float*)d_in[5];
    const float* tmr   = (const float*)d_in[6];
    const float* dw    = (const float*)d_in[7];
    const float* Wk    = (const float*)d_in[8];
    const float* Wv    = (const float*)d_in[9];
    const float* Wr    = (const float*)d_in[10];
    const float* Wo    = (const float*)d_in[11];
    float* out = (float*)d_out;

    const int WN = D_MODEL * D_MODEL;             // 1048576
    const size_t MATN = (size_t)NROWS * D_MODEL;  // 16777216

    bf16* wsb  = (bf16*)d_ws;
    bf16* Wk_b = wsb;
    bf16* Wv_b = Wk_b + WN;
    bf16* Wr_b = Wv_b + WN;
    bf16* Wo_b = Wr_b + WN;
    // 4 matrix slots with liveness-based reuse:
    bf16* s0_ = Wo_b + WN;   // XK, later Vt
    bf16* s1_ = s0_ + MATN;  // XV, later R
    bf16* s2_ = s1_ + MATN;  // XR, later S_all
    bf16* s3_ = s2_ + MATN;  // Kt
    bf16* XK = s0_, *XV = s1_, *XR = s2_;
    bf16* Kt = s3_, *Vt = s0_, *RB = s1_, *SA = s2_;

    conv_w_kernel<<<1024, 256, 0, stream>>>(Wk, Wk_b, WN);
    conv_w_kernel<<<1024, 256, 0, stream>>>(Wv, Wv_b, WN);
    conv_w_kernel<<<1024, 256, 0, stream>>>(Wr, Wr_b, WN);
    conv_w_kernel<<<1024, 256, 0, stream>>>(Wo, Wo_b, WN);

    lnmix_kernel<<<NROWS / 4, 256, 0, stream>>>(x, gamma, beta, tmk, tmv, tmr, XK, XV, XR);

    dim3 ggrid(D_MODEL / 128, NROWS / 128);   // (8, 128)
    gemm_tn_kernel<0><<<ggrid, 256, 0, stream>>>(XK, Wk_b, Kt);
    gemm_tn_kernel<0><<<ggrid, 256, 0, stream>>>(XV, Wv_b, Vt);
    gemm_tn_kernel<1><<<ggrid, 256, 0, stream>>>(XR, Wr_b, RB);

    scan_kernel<<<dim3(D_MODEL / 64, BATCH), 256, 0, stream>>>(Kt, Vt, dw, S0, SA, out + MATN);

    gemm_out_kernel<<<ggrid, 256, 0, stream>>>(SA, Wo_b, RB, x, out);
}